// Round 1
// baseline (79.432 us; speedup 1.0000x reference)
//
#include <hip/hip_runtime.h>

#define S_DEPTH 128
#define N_RES   512
#define E_DIM   256
#define P_DIM   32
#define C_DIM   128

typedef short bh8 __attribute__((ext_vector_type(8)));   // 8 x bf16 (as raw shorts)
typedef float fx4 __attribute__((ext_vector_type(4)));   // MFMA f32 accumulator

__device__ __forceinline__ unsigned short f2bf(float x){
    unsigned int u = __builtin_bit_cast(unsigned int, x);
    u += 0x7fffu + ((u >> 16) & 1u);          // round-to-nearest-even
    return (unsigned short)(u >> 16);
}

// ---------------------------------------------------------------------------
// K0: transpose weights into bf16 fragment-friendly layouts.
//   WaT/WbT: [P][E]  (E contiguous)  -> A-operand rows = p
//   WpT:     [C][P]  (P contiguous)  -> B-operand cols = c, k = p
// ---------------------------------------------------------------------------
__global__ void prep_kernel(const float* __restrict__ Wa, const float* __restrict__ Wb,
                            const float* __restrict__ Wp,
                            unsigned short* __restrict__ WaT, unsigned short* __restrict__ WbT,
                            unsigned short* __restrict__ WpT){
    int t = threadIdx.x;                       // 256 threads
    for (int i = 0; i < 32; ++i){              // 8192 = P*E
        int idx = i * 256 + t;
        int p = idx >> 8, e = idx & 255;       // idx = p*256 + e
        WaT[idx] = f2bf(Wa[e * P_DIM + p]);
        WbT[idx] = f2bf(Wb[e * P_DIM + p]);
    }
    for (int i = 0; i < 16; ++i){              // 4096 = C*P
        int idx = i * 256 + t;
        int c = idx >> 5, p = idx & 31;        // idx = c*32 + p
        WpT[idx] = f2bf(Wp[p * C_DIM + c]);
    }
}

// ---------------------------------------------------------------------------
// K1: LayerNorm + dual projection. One block per residue n0.
//   Computes aT[p][n0][s], bT[p][n0][s] (bf16, s contiguous) for all p,s.
//   Phase 1: f32 LN of x[s][n0][:] -> bf16 rows in XOR-swizzled LDS.
//   Phase 2: MFMA  D[p][s] = WaT[p][:] @ xn[:][s]   (M=32, N=128, K=256)
// ---------------------------------------------------------------------------
__global__ __launch_bounds__(256) void lnproj_kernel(
    const float* __restrict__ x, const float* __restrict__ gamma, const float* __restrict__ beta,
    const unsigned short* __restrict__ WaT, const unsigned short* __restrict__ WbT,
    const float* __restrict__ ba, const float* __restrict__ bb,
    unsigned short* __restrict__ aT, unsigned short* __restrict__ bT)
{
    __shared__ __align__(16) char smem[S_DEPTH * E_DIM * 2];   // 128 rows x 512 B = 64 KB
    const int n0   = blockIdx.x;
    const int tid  = threadIdx.x;
    const int lane = tid & 63;
    const int w    = tid >> 6;          // 4 waves
    const int l15  = lane & 15;
    const int lq   = lane >> 4;

    const float4 g4 = *(const float4*)(gamma + lane * 4);
    const float4 b4 = *(const float4*)(beta  + lane * 4);

    // ---- phase 1: LN, 32 rows (s values) per wave ----
    for (int rr = 0; rr < 32; ++rr){
        int s = w * 32 + rr;
        float4 v = *(const float4*)(x + ((size_t)(s * N_RES + n0)) * E_DIM + lane * 4);
        float sum = v.x + v.y + v.z + v.w;
        float sq  = v.x*v.x + v.y*v.y + v.z*v.z + v.w*v.w;
        #pragma unroll
        for (int m = 1; m < 64; m <<= 1){
            sum += __shfl_xor(sum, m);
            sq  += __shfl_xor(sq,  m);
        }
        float mu  = sum * (1.0f / E_DIM);
        float inv = rsqrtf(sq * (1.0f / E_DIM) - mu * mu + 1e-5f);
        ushort4 pk;
        pk.x = f2bf((v.x - mu) * inv * g4.x + b4.x);
        pk.y = f2bf((v.y - mu) * inv * g4.y + b4.y);
        pk.z = f2bf((v.z - mu) * inv * g4.z + b4.z);
        pk.w = f2bf((v.w - mu) * inv * g4.w + b4.w);
        int boff = s * 512 + lane * 8;       // row = 512 B
        boff ^= (s & 7) << 4;                // XOR swizzle (kills 16-way read conflict)
        *(ushort4*)(smem + boff) = pk;
    }
    __syncthreads();

    // ---- phase 2: MFMA projection. Wave w owns s-tiles {2w, 2w+1}. ----
    fx4 accA[2][2], accB[2][2];              // [s-tile][p-tile]
    #pragma unroll
    for (int st = 0; st < 2; ++st)
        #pragma unroll
        for (int pt = 0; pt < 2; ++pt){
            accA[st][pt] = fx4{0.f, 0.f, 0.f, 0.f};
            accB[st][pt] = fx4{0.f, 0.f, 0.f, 0.f};
        }

    #pragma unroll
    for (int ks = 0; ks < 8; ++ks){          // K = 256 = 8 x 32
        bh8 wa[2], wb[2];
        #pragma unroll
        for (int pt = 0; pt < 2; ++pt){
            int off = (pt * 16 + l15) * E_DIM + ks * 32 + lq * 8;   // A: row p, 8 contig k
            wa[pt] = *(const bh8*)(WaT + off);
            wb[pt] = *(const bh8*)(WbT + off);
        }
        #pragma unroll
        for (int st = 0; st < 2; ++st){
            int srow = (w * 2 + st) * 16 + l15;                     // B: col s, 8 contig k
            int boff = srow * 512 + (ks * 32 + lq * 8) * 2;
            boff ^= (srow & 7) << 4;
            bh8 xf = *(const bh8*)(smem + boff);
            #pragma unroll
            for (int pt = 0; pt < 2; ++pt){
                accA[st][pt] = __builtin_amdgcn_mfma_f32_16x16x32_bf16(wa[pt], xf, accA[st][pt], 0, 0, 0);
                accB[st][pt] = __builtin_amdgcn_mfma_f32_16x16x32_bf16(wb[pt], xf, accB[st][pt], 0, 0, 0);
            }
        }
    }

    // ---- epilogue: D col = lane&15 (s), row = (lane>>4)*4 + reg (p) ----
    #pragma unroll
    for (int st = 0; st < 2; ++st){
        int s = (w * 2 + st) * 16 + l15;
        #pragma unroll
        for (int pt = 0; pt < 2; ++pt){
            #pragma unroll
            for (int j = 0; j < 4; ++j){
                int p = pt * 16 + lq * 4 + j;
                size_t o = ((size_t)p * N_RES + n0) * S_DEPTH + s;
                aT[o] = f2bf(accA[st][pt][j] + ba[p]);
                bT[o] = f2bf(accB[st][pt][j] + bb[p]);
            }
        }
    }
}

// ---------------------------------------------------------------------------
// K2: fused batched outer-product (mean over S) + Wp projection + bias.
//   One block per 32x32 (n,m) tile. 8 waves; wave w owns p-quad {4w..4w+3}.
//   Stage 1: outer[n,m,p]/S -> bf16 LDS [nm=1024][p=32]  (64 KB)
//   Stage 2: out[n,m,c] = LDS[nm][:] @ WpT + bp   (K=32 -> single MFMA)
// ---------------------------------------------------------------------------
__global__ __launch_bounds__(512) void outer_kernel(
    const unsigned short* __restrict__ aT, const unsigned short* __restrict__ bT,
    const unsigned short* __restrict__ WpT, const float* __restrict__ bp,
    float* __restrict__ out)
{
    __shared__ __align__(16) char smem[1024 * 64];   // [nm][p] bf16 = 64 KB
    const int tn = blockIdx.x >> 4, tm = blockIdx.x & 15;
    const int n0 = tn * 32, m0 = tm * 32;
    const int tid  = threadIdx.x;
    const int lane = tid & 63;
    const int w    = tid >> 6;          // 8 waves
    const int l15  = lane & 15;
    const int lq   = lane >> 4;

    // ---- stage 1: batched outer products ----
    #pragma unroll
    for (int q = 0; q < 4; ++q){
        int p = w * 4 + q;
        fx4 acc[2][2];
        #pragma unroll
        for (int ti = 0; ti < 2; ++ti)
            #pragma unroll
            for (int tj = 0; tj < 2; ++tj)
                acc[ti][tj] = fx4{0.f, 0.f, 0.f, 0.f};

        #pragma unroll
        for (int ks = 0; ks < 4; ++ks){    // K = S = 128 = 4 x 32
            bh8 af[2], bfv[2];
            #pragma unroll
            for (int t = 0; t < 2; ++t){
                af[t]  = *(const bh8*)(aT + ((size_t)p * N_RES + n0 + t * 16 + l15) * S_DEPTH + ks * 32 + lq * 8);
                bfv[t] = *(const bh8*)(bT + ((size_t)p * N_RES + m0 + t * 16 + l15) * S_DEPTH + ks * 32 + lq * 8);
            }
            #pragma unroll
            for (int ti = 0; ti < 2; ++ti)
                #pragma unroll
                for (int tj = 0; tj < 2; ++tj)
                    acc[ti][tj] = __builtin_amdgcn_mfma_f32_16x16x32_bf16(af[ti], bfv[tj], acc[ti][tj], 0, 0, 0);
        }
        // write outer/S to LDS (D: col m = lane&15, row n = lq*4+reg)
        #pragma unroll
        for (int ti = 0; ti < 2; ++ti)
            #pragma unroll
            for (int tj = 0; tj < 2; ++tj)
                #pragma unroll
                for (int j = 0; j < 4; ++j){
                    int nloc = ti * 16 + lq * 4 + j;
                    int mloc = tj * 16 + l15;
                    int nm = nloc * 32 + mloc;
                    *(unsigned short*)(smem + nm * 64 + p * 2) =
                        f2bf(acc[ti][tj][j] * (1.0f / S_DEPTH));
                }
    }
    __syncthreads();

    // ---- stage 2: project P -> C, fused bias, write f32 out ----
    bh8   wpf[8];
    float bpv[8];
    #pragma unroll
    for (int ct = 0; ct < 8; ++ct){
        wpf[ct] = *(const bh8*)(WpT + (ct * 16 + l15) * P_DIM + lq * 8);  // B: col c, k = p
        bpv[ct] = bp[ct * 16 + l15];
    }
    #pragma unroll
    for (int mi = 0; mi < 8; ++mi){
        int mt = w * 8 + mi;                               // 64 nm-tiles / 8 waves
        bh8 of = *(const bh8*)(smem + (mt * 16 + l15) * 64 + lq * 16);    // A: row nm, k = p
        #pragma unroll
        for (int ct = 0; ct < 8; ++ct){
            fx4 d = __builtin_amdgcn_mfma_f32_16x16x32_bf16(
                        of, wpf[ct], fx4{0.f, 0.f, 0.f, 0.f}, 0, 0, 0);
            #pragma unroll
            for (int j = 0; j < 4; ++j){
                int nm = mt * 16 + lq * 4 + j;
                int n = n0 + (nm >> 5), m = m0 + (nm & 31);
                out[((size_t)n * N_RES + m) * C_DIM + ct * 16 + l15] = d[j] + bpv[ct];
            }
        }
    }
}

// ---------------------------------------------------------------------------
extern "C" void kernel_launch(void* const* d_in, const int* in_sizes, int n_in,
                              void* d_out, int out_size, void* d_ws, size_t ws_size,
                              hipStream_t stream){
    const float* msa   = (const float*)d_in[0];
    const float* gamma = (const float*)d_in[1];
    const float* beta  = (const float*)d_in[2];
    const float* Wa    = (const float*)d_in[3];
    const float* ba    = (const float*)d_in[4];
    const float* Wb    = (const float*)d_in[5];
    const float* bb    = (const float*)d_in[6];
    const float* Wp    = (const float*)d_in[7];
    const float* bp    = (const float*)d_in[8];
    float* out = (float*)d_out;

    // workspace layout (ushort elements): aT | bT | WaT | WbT | WpT  (~8.04 MB)
    unsigned short* ws  = (unsigned short*)d_ws;
    unsigned short* aT  = ws;                        // 32*512*128 = 2097152
    unsigned short* bT  = ws + 2097152;
    unsigned short* WaT = ws + 4194304;              // 8192
    unsigned short* WbT = WaT + 8192;                // 8192
    unsigned short* WpT = WbT + 8192;                // 4096

    prep_kernel<<<1, 256, 0, stream>>>(Wa, Wb, Wp, WaT, WbT, WpT);
    lnproj_kernel<<<N_RES, 256, 0, stream>>>(msa, gamma, beta, WaT, WbT, ba, bb, aT, bT);
    outer_kernel<<<256, 512, 0, stream>>>(aT, bT, WpT, bp, out);
}